// Round 10
// baseline (14.045 us; speedup 1.0000x reference)
//
#include <hip/hip_runtime.h>
#include <math.h>

#define BB 128
#define CC 1024
#define SPLIT 64                 // blocks per batch
#define NBLK (BB * SPLIT)        // 8192
#define CAP 256                  // jw LDS capacity (n ~ 51; exact fallback past CAP)
#define INV_N (1.0f / (float)(BB * CC))

// k1: 8192 single-wave blocks (32/CU = max wave occupancy). Per block:
// lane-major row load -> popcount+scan compaction -> AT MOST ONE positive
// gather round (SPLIT=64 > n~51) -> negatives (chunks 0..15) -> partial.
__global__ __launch_bounds__(64) void asl_main_kernel(
    const float* __restrict__ x, const float* __restrict__ y,
    const float* __restrict__ mask, float* __restrict__ partial) {
  const int blk   = blockIdx.x;
  const int b     = blk & (BB - 1);   // consecutive blocks: different batch
  const int chunk = blk >> 7;         // 0..63
  const int lane  = threadIdx.x;

  __shared__ unsigned short jidx[CC];   // 2 KB
  __shared__ float          jw[CAP];    // 1 KB

  const float* xb = x + (size_t)b * CC;
  const float* yb = y + (size_t)b * CC;

  // ---- y row, lane-major: lane owns elements 16*lane .. 16*lane+15 ----
  const float4* y4 = (const float4*)yb;
  float4 yq[4];
#pragma unroll
  for (int c = 0; c < 4; ++c) yq[c] = y4[4 * lane + c];
  const float yv[16] = {yq[0].x, yq[0].y, yq[0].z, yq[0].w,
                        yq[1].x, yq[1].y, yq[1].z, yq[1].w,
                        yq[2].x, yq[2].y, yq[2].z, yq[2].w,
                        yq[3].x, yq[3].y, yq[3].z, yq[3].w};
  unsigned m = 0;
#pragma unroll
  for (int t = 0; t < 16; ++t) m |= (yv[t] != 0.0f) ? (1u << t) : 0u;
  const int cnt = __popc(m);

  // ---- 6-step inclusive scan over lane counts ----
  int inc = cnt;
#pragma unroll
  for (int o = 1; o < 64; o <<= 1) {
    const int t = __shfl_up(inc, o, 64);
    if (lane >= o) inc += t;
  }
  const int n     = __shfl(inc, 63, 64);   // total positives (wave-uniform)
  const int base0 = inc - cnt;             // this lane's exclusive offset

  // ---- early-out: positive-only block with no owned entry ----
  if (chunk >= 16 && chunk >= n) {
    if (lane == 0) partial[blk] = 0.0f;
    return;
  }

  // ---- x row, lane-major; write compacted entries ----
  const float4* x4 = (const float4*)xb;
  float4 xq[4];
#pragma unroll
  for (int c = 0; c < 4; ++c) xq[c] = x4[4 * lane + c];
  const float xv[16] = {xq[0].x, xq[0].y, xq[0].z, xq[0].w,
                        xq[1].x, xq[1].y, xq[1].z, xq[1].w,
                        xq[2].x, xq[2].y, xq[2].z, xq[2].w,
                        xq[3].x, xq[3].y, xq[3].z, xq[3].w};
  int pos = base0;
#pragma unroll
  for (int t = 0; t < 16; ++t) {
    if (m & (1u << t)) {
      jidx[pos] = (unsigned short)(16 * lane + t);
      if (pos < CAP) jw[pos] = xv[t] * xv[t];
      ++pos;
    }
  }

  float acc = 0.0f;

  // ---- positive: at most one entry (e = chunk; SPLIT=64 > typical n) ----
  for (int e = chunk; e < n; e += SPLIT) {
    const int ii = jidx[e];                        // uniform LDS broadcast
    const float* mrow = mask + (size_t)ii * CC;
    float mm = 0.0f;
    for (int k = lane; k < n; k += 64) {
      const int j = jidx[k];
      float w;
      if (k < CAP) w = jw[k];
      else { const float xg = xb[j]; w = xg * xg; }  // exact, never taken (n<=CAP)
      mm = fmaxf(mm, mrow[j] * w);                 // mask 0/1; diag => mm>0
    }
#pragma unroll
    for (int o = 32; o > 0; o >>= 1)
      mm = fmaxf(mm, __shfl_xor(mm, o, 64));
    if (lane == 0) acc += logf(mm);                // GAMMA_POS=0 -> log(xp)
  }

  // ---- negatives: chunks 0..15 cover i = chunk*64 + lane ----
  if (chunk < 16) {
    const int   i  = chunk * 64 + lane;
    const float xi = xb[i];                        // L1-hot (row just loaded)
    const float yi = yb[i];
    if (yi == 0.0f) {
      const float x2 = xi * xi;
      acc += (x2 * x2) * logf(1.0f - xi);          // xp = x; xp^4*log(1-xp)
    }
  }

  // ---- wave reduce, publish ----
#pragma unroll
  for (int o = 32; o > 0; o >>= 1)
    acc += __shfl_down(acc, o, 64);
  if (lane == 0) partial[blk] = acc;
}

// Deterministic NBLK -> 1 reduction, negated mean. float4 loads.
__global__ __launch_bounds__(256) void asl_final_kernel(
    const float* __restrict__ partial, float* __restrict__ out) {
  const int tid = threadIdx.x;
  const float4* p4 = (const float4*)partial;
  float v = 0.0f;
#pragma unroll
  for (int r = 0; r < NBLK / 4 / 256; ++r) {
    const float4 q = p4[tid + 256 * r];
    v += (q.x + q.y) + (q.z + q.w);
  }
#pragma unroll
  for (int o = 32; o > 0; o >>= 1)
    v += __shfl_down(v, o, 64);
  __shared__ float s[4];
  if ((tid & 63) == 0) s[tid >> 6] = v;
  __syncthreads();
  if (tid == 0) out[0] = -(s[0] + s[1] + s[2] + s[3]) * INV_N;
}

extern "C" void kernel_launch(void* const* d_in, const int* in_sizes, int n_in,
                              void* d_out, int out_size, void* d_ws, size_t ws_size,
                              hipStream_t stream) {
  const float* x    = (const float*)d_in[0];
  const float* y    = (const float*)d_in[1];
  const float* mask = (const float*)d_in[2];
  float* out     = (float*)d_out;
  float* partial = (float*)d_ws;   // NBLK floats, fully rewritten each call

  asl_main_kernel<<<NBLK, 64, 0, stream>>>(x, y, mask, partial);
  asl_final_kernel<<<1, 256, 0, stream>>>(partial, out);
}

// Round 11
// 11.563 us; speedup vs baseline: 1.2147x; 1.2147x over previous
//
#include <hip/hip_runtime.h>
#include <math.h>

#define BB 128
#define CC 1024
#define SPLIT 32                 // blocks per batch
#define NBLK (BB * SPLIT)        // 4096
#define INV_N (1.0f / (float)(BB * CC))

// R9 structure with FUSED gather pairs: blocks owning two positive entries
// (e, e+32) issue both 64-lane mask-row gathers back-to-back before either
// shuffle-reduce -> one exposed memory latency instead of two. Accumulation
// order identical to R9 (logf(e) then logf(e+32)) -> bit-identical result.
__global__ __launch_bounds__(64) void asl_main_kernel(
    const float* __restrict__ x, const float* __restrict__ y,
    const float* __restrict__ mask, float* __restrict__ partial) {
  const int blk   = blockIdx.x;
  const int b     = blk & (BB - 1);   // consecutive blocks: different batch
  const int chunk = blk >> 7;         // 0..31
  const int lane  = threadIdx.x;

  __shared__ unsigned short jidx[CC];
  __shared__ float          jw[CC];

  const float* xb = x + (size_t)b * CC;
  const float* yb = y + (size_t)b * CC;

  // Full row into registers for compaction.
  const float4* x4 = (const float4*)xb;
  const float4* y4 = (const float4*)yb;
  float4 xq[4], yq[4];
#pragma unroll
  for (int c = 0; c < 4; ++c) {
    xq[c] = x4[lane + 64 * c];
    yq[c] = y4[lane + 64 * c];
  }

  // Negative-term inputs: one i per lane (scalar loads, cache-hot).
  const int   i  = (chunk & 15) * 64 + lane;   // chunks 0..15 use these
  const float xi = xb[i];
  const float yi = yb[i];

  // ---- compaction: 16 ballots, deterministic order ----
  int base = 0;
#pragma unroll
  for (int c = 0; c < 4; ++c) {
    const float yv[4] = {yq[c].x, yq[c].y, yq[c].z, yq[c].w};
    const float xv[4] = {xq[c].x, xq[c].y, xq[c].z, xq[c].w};
#pragma unroll
    for (int q = 0; q < 4; ++q) {
      const bool p = (yv[q] != 0.0f);
      const unsigned long long bal = __ballot(p);
      if (p) {
        const int pos = base + __popcll(bal & ((1ull << lane) - 1ull));
        jidx[pos] = (unsigned short)(4 * (lane + 64 * c) + q);
        jw[pos]   = xv[q] * xv[q];
      }
      base += __popcll(bal);
    }
  }
  const int n = base;  // wave-uniform

  float acc = 0.0f;

  // ---- positives: fused pairs (e, e+SPLIT); both gathers in flight at once ----
  for (int e = chunk; e < n; e += 2 * SPLIT) {
    const int eB = e + SPLIT;
    const bool hB = (eB < n);
    const float* mrowA = mask + (size_t)jidx[e] * CC;        // uniform broadcast
    const float* mrowB = hB ? mask + (size_t)jidx[eB] * CC : mrowA;  // safe ptr
    float mmA = 0.0f, mmB = 0.0f;
    for (int k = lane; k < n; k += 64) {                     // one iter (n<=64)
      const int   j = jidx[k];
      const float w = jw[k];
      mmA = fmaxf(mmA, mrowA[j] * w);                        // mask 0/1; diag => mm>0
      mmB = fmaxf(mmB, mrowB[j] * w);
    }
#pragma unroll
    for (int o = 32; o > 0; o >>= 1) {
      mmA = fmaxf(mmA, __shfl_xor(mmA, o, 64));
      mmB = fmaxf(mmB, __shfl_xor(mmB, o, 64));
    }
    if (lane == 0) {
      acc += logf(mmA);                                      // GAMMA_POS=0 -> log(xp)
      if (hB) acc += logf(mmB);
    }
  }

  // ---- negatives: chunks 0..15 cover i = chunk*64 + lane ----
  if (chunk < 16) {
    if (yi == 0.0f) {
      const float x2 = xi * xi;
      acc += (x2 * x2) * logf(1.0f - xi);          // xp = x; xp^4*log(1-xp)
    }
  }

  // ---- wave reduce, publish ----
#pragma unroll
  for (int o = 32; o > 0; o >>= 1)
    acc += __shfl_down(acc, o, 64);
  if (lane == 0) partial[blk] = acc;
}

// Deterministic NBLK -> 1 reduction, negated mean. float4 loads.
__global__ __launch_bounds__(256) void asl_final_kernel(
    const float* __restrict__ partial, float* __restrict__ out) {
  const int tid = threadIdx.x;
  const float4* p4 = (const float4*)partial;
  float v = 0.0f;
#pragma unroll
  for (int r = 0; r < NBLK / 4 / 256; ++r) {
    const float4 q = p4[tid + 256 * r];
    v += (q.x + q.y) + (q.z + q.w);
  }
#pragma unroll
  for (int o = 32; o > 0; o >>= 1)
    v += __shfl_down(v, o, 64);
  __shared__ float s[4];
  if ((tid & 63) == 0) s[tid >> 6] = v;
  __syncthreads();
  if (tid == 0) out[0] = -(s[0] + s[1] + s[2] + s[3]) * INV_N;
}

extern "C" void kernel_launch(void* const* d_in, const int* in_sizes, int n_in,
                              void* d_out, int out_size, void* d_ws, size_t ws_size,
                              hipStream_t stream) {
  const float* x    = (const float*)d_in[0];
  const float* y    = (const float*)d_in[1];
  const float* mask = (const float*)d_in[2];
  float* out     = (float*)d_out;
  float* partial = (float*)d_ws;   // NBLK floats, fully rewritten each call

  asl_main_kernel<<<NBLK, 64, 0, stream>>>(x, y, mask, partial);
  asl_final_kernel<<<1, 256, 0, stream>>>(partial, out);
}